// Round 19
// baseline (105.217 us; speedup 1.0000x reference)
//
#include <hip/hip_runtime.h>

// MSSFM round 19 — r18 (91.4us) + two independent changes:
//   1. k_scan -> k_scan_par: 4-way chunked affine scan (SRU recurrence is
//      affine-associative). 65536->262144 threads (4->16 waves/CU), z/f held
//      in regs between passes, 4-step LDS prefix. Same memory traffic.
//   2. k_mega: Bt LDS staging deleted — gemm0 reads y1 fragments directly
//      from g_y1 (L2 stream); one less barrier.
// HARD RULE: static LDS <= 64KB. exp INTRINSICS segfault this clang (r8/r9)
// — hardware exp2/rcp via inline asm (r13-validated).

typedef __bf16 bf16x8 __attribute__((ext_vector_type(8)));
typedef __bf16 bf16x4 __attribute__((ext_vector_type(4)));
typedef __bf16 bf16x2 __attribute__((ext_vector_type(2)));
typedef float  f32x4  __attribute__((ext_vector_type(4)));

constexpr int kHW = 16384;   // 128*128

__device__ __align__(16) __bf16 g_y1[8388608];    // NHWC bf16
__device__ __align__(16) __bf16 g_ZF[16777216];   // [pixel][2c]={Z,F}
__device__ __align__(16) __bf16 g_S [8388608];    // sigmoid(y2), NHWC
// g_w: f1w1@0 f1w2@16384 f2w1@32768 f2w2@49152 pw1@65536 pw2@98304
//      A1@131072[128][96] A4@143360[128][96] pw3@155648
__device__ __align__(16) __bf16 g_w [172032];

__device__ __forceinline__ float hw_exp2(float x)
{
    float r;
    asm("v_exp_f32 %0, %1" : "=v"(r) : "v"(x));
    return r;
}
__device__ __forceinline__ float hw_rcp(float x)
{
    float r;
    asm("v_rcp_f32 %0, %1" : "=v"(r) : "v"(x));
    return r;
}
__device__ __forceinline__ float fast_tanh(float x)
{
    return 1.f - 2.f * hw_rcp(hw_exp2(2.88539008f * x) + 1.f);
}
__device__ __forceinline__ float fast_sig(float x)
{
    return hw_rcp(1.f + hw_exp2(-1.44269504f * x));
}
__device__ __forceinline__ float fast_gelu(float x)
{
    return 0.5f * x * (1.f + fast_tanh(0.79788456f * (x + 0.044715f * x * x * x)));
}

// ---------------- pack weights to bf16 --------------------------------------
__global__ __launch_bounds__(256) void k_prepw(
    const float* __restrict__ f1w1, const float* __restrict__ f1w2,
    const float* __restrict__ f2w1, const float* __restrict__ f2w2,
    const float* __restrict__ pw1, const float* __restrict__ pw2,
    const float* __restrict__ d1w, const float* __restrict__ d4w,
    const float* __restrict__ pw3)
{
    int idx = blockIdx.x * 256 + threadIdx.x;  // 172032
    float v;
    if (idx < 16384)        v = f1w1[idx];
    else if (idx < 32768)   v = f1w2[idx - 16384];
    else if (idx < 49152)   v = f2w1[idx - 32768];
    else if (idx < 65536)   v = f2w2[idx - 49152];
    else if (idx < 98304)   v = pw1[idx - 65536];
    else if (idx < 131072)  v = pw2[idx - 98304];
    else if (idx < 155648) {
        // A1/A4: [128 c][96 k], k = tap*8+s (tap=kh*3+kw), taps 9..11 zero
        int r = idx - 131072;
        const float* src = d1w;
        if (r >= 12288) { r -= 12288; src = d4w; }
        int c = r / 96, k = r - c * 96;
        int tap = k >> 3, s = k & 7;
        v = (tap < 9) ? src[c * 72 + s * 9 + tap] : 0.f;
    } else                  v = pw3[idx - 155648];
    g_w[idx] = (__bf16)v;
}

// ---------------- fused: DPB conv + dual-branch prescan (512 thr) -----------
__global__ __launch_bounds__(512) void k_fused(
    const float* __restrict__ x, const float* __restrict__ d1b,
    const float* __restrict__ d4b, const float* __restrict__ pa,
    const float* __restrict__ f1b1, const float* __restrict__ f1b2,
    const float* __restrict__ f2b1, const float* __restrict__ f2b2)
{
    __shared__ __align__(16) char U1[17408];   // Bt[64][136], then Tz[64][136]
    __shared__ __align__(16) char U2[17408];   // patch[5][80][8], then Tf[64][136]
    auto Bt    = (__bf16 (*)[136])U1;
    auto Tz    = (__bf16 (*)[136])U1;
    auto patch = (__bf16 (*)[80][8])U2;
    auto Tf    = (__bf16 (*)[136])U2;

    const int tid = threadIdx.x;
    const int n0 = blockIdx.x * 64;            // global pixel base
    const int b = n0 >> 14, hw0 = n0 & 16383;
    const int h = hw0 >> 7, w0 = hw0 & 127;

    // ---- stage x patch: rows {h-7,h-1,h,h+1,h+7} x cols [w0-7, w0+70] ------
    const int roff[5] = {-7, -1, 0, 1, 7};
    if (tid < 400) {
        int rs = tid / 80, c = tid - rs * 80;
        int row = h + roff[rs], wc = w0 + c - 7;
        bf16x8 v;
#pragma unroll
        for (int s = 0; s < 8; ++s) v[s] = (__bf16)0.f;
        if ((unsigned)row < 128u && (unsigned)wc < 128u && c < 78) {
#pragma unroll
            for (int s = 0; s < 8; ++s)
                v[s] = (__bf16)x[(size_t)(b * 8 + s) * kHW + row * 128 + wc];
        }
        *(bf16x8*)&patch[rs][c][0] = v;
    }

    const int lane = tid & 63, wid = tid >> 6;   // wid 0..7, 16-row M slice
    const int fr = lane & 15, kg = (lane >> 4) << 3, mrow = (lane >> 4) << 2;
    const int mbase = wid * 16;

    f32x4 acc1[4], acc4[4];
#pragma unroll
    for (int nt = 0; nt < 4; ++nt)
#pragma unroll
        for (int r = 0; r < 4; ++r) { acc1[nt][r] = 0.f; acc4[nt][r] = 0.f; }

    __syncthreads();   // patch ready

#pragma unroll
    for (int cv = 0; cv < 2; ++cv) {
        const __bf16* Ag = g_w + (cv ? 143360 : 131072);
#pragma unroll
        for (int k0 = 0; k0 < 96; k0 += 32) {
            bf16x8 af = *(const bf16x8*)&Ag[(size_t)(mbase + fr) * 96 + k0 + kg];
            int tap = (k0 + kg) >> 3;   // uniform within a 16-lane group
            bf16x8 bfr[4];
#pragma unroll
            for (int nt = 0; nt < 4; ++nt) {
                bf16x8 bv;
#pragma unroll
                for (int i = 0; i < 8; ++i) bv[i] = (__bf16)0.f;
                if (tap < 9) {
                    int dh = tap / 3 - 1, dw = tap % 3 - 1;
                    int rowsel = cv ? (dh + 1) * 2 : dh + 2;
                    int col = nt * 16 + fr + dw * (cv ? 7 : 1) + 7;
                    bv = *(const bf16x8*)&patch[rowsel][col][0];
                }
                bfr[nt] = bv;
            }
            if (cv == 0) {
#pragma unroll
                for (int nt = 0; nt < 4; ++nt)
                    acc1[nt] = __builtin_amdgcn_mfma_f32_16x16x32_bf16(af, bfr[nt], acc1[nt], 0, 0, 0);
            } else {
#pragma unroll
                for (int nt = 0; nt < 4; ++nt)
                    acc4[nt] = __builtin_amdgcn_mfma_f32_16x16x32_bf16(af, bfr[nt], acc4[nt], 0, 0, 0);
            }
        }
    }

    __syncthreads();   // all patch reads done before Bt writes land in U1-adjacent timing

    // ---- epilogue: y1 = prelu + prelu -> Bt (LDS, U1) + g_y1 (NHWC) ----
    const float pav = pa[0];
    {
        int m = mbase + mrow;
        f32x4 b1v = *(const f32x4*)&d1b[m];
        f32x4 b4v = *(const f32x4*)&d4b[m];
#pragma unroll
        for (int nt = 0; nt < 4; ++nt) {
            int nl = nt * 16 + fr;
            bf16x4 o;
#pragma unroll
            for (int r = 0; r < 4; ++r) {
                float v1 = acc1[nt][r] + b1v[r];
                float v4 = acc4[nt][r] + b4v[r];
                v1 = (v1 >= 0.f) ? v1 : pav * v1;
                v4 = (v4 >= 0.f) ? v4 : pav * v4;
                o[r] = (__bf16)(v1 + v4);
            }
            *(bf16x4*)&Bt[nl][m] = o;
            *(bf16x4*)&g_y1[(size_t)(n0 + nl) * 128 + m] = o;
        }
    }
    __syncthreads();   // Bt fully written; patch dead

    // ---- prescan phase 1 (dual): t1 = tanh(W11.y1+b), t2 = tanh(W21.y1+b) --
    {
        f32x4 az[4], afc[4];
#pragma unroll
        for (int nt = 0; nt < 4; ++nt)
#pragma unroll
            for (int r = 0; r < 4; ++r) { az[nt][r] = 0.f; afc[nt][r] = 0.f; }
#pragma unroll
        for (int k0 = 0; k0 < 128; k0 += 32) {
            size_t rowoff = (size_t)(mbase + fr) * 128 + k0 + kg;
            bf16x8 wz = *(const bf16x8*)&g_w[rowoff];            // f1w1
            bf16x8 wf = *(const bf16x8*)&g_w[32768 + rowoff];    // f2w1
            bf16x8 bfr[4];
#pragma unroll
            for (int nt = 0; nt < 4; ++nt)
                bfr[nt] = *(const bf16x8*)&Bt[nt * 16 + fr][k0 + kg];
#pragma unroll
            for (int nt = 0; nt < 4; ++nt) {
                az[nt]  = __builtin_amdgcn_mfma_f32_16x16x32_bf16(wz, bfr[nt], az[nt], 0, 0, 0);
                afc[nt] = __builtin_amdgcn_mfma_f32_16x16x32_bf16(wf, bfr[nt], afc[nt], 0, 0, 0);
            }
        }
        __syncthreads();   // ALL Bt reads complete -> Tz may overwrite U1
        int m = mbase + mrow;
        f32x4 bz = *(const f32x4*)&f1b1[m];
        f32x4 bfv = *(const f32x4*)&f2b1[m];
#pragma unroll
        for (int nt = 0; nt < 4; ++nt) {
            int nl = nt * 16 + fr;
            bf16x4 oz, of;
#pragma unroll
            for (int r = 0; r < 4; ++r) {
                oz[r] = (__bf16)fast_tanh(az[nt][r] + bz[r]);
                of[r] = (__bf16)fast_tanh(afc[nt][r] + bfv[r]);
            }
            *(bf16x4*)&Tz[nl][m] = oz;
            *(bf16x4*)&Tf[nl][m] = of;
        }
    }
    __syncthreads();   // Tz/Tf ready

    // ---- prescan phase 2 (dual): Z = tanh(W12.t1+b), F = sig(W22.t2+b) -----
    {
        f32x4 az[4], afc[4];
#pragma unroll
        for (int nt = 0; nt < 4; ++nt)
#pragma unroll
            for (int r = 0; r < 4; ++r) { az[nt][r] = 0.f; afc[nt][r] = 0.f; }
#pragma unroll
        for (int k0 = 0; k0 < 128; k0 += 32) {
            size_t rowoff = (size_t)(mbase + fr) * 128 + k0 + kg;
            bf16x8 wz = *(const bf16x8*)&g_w[16384 + rowoff];    // f1w2
            bf16x8 wf = *(const bf16x8*)&g_w[49152 + rowoff];    // f2w2
            bf16x8 bz[4], bf[4];
#pragma unroll
            for (int nt = 0; nt < 4; ++nt) {
                bz[nt] = *(const bf16x8*)&Tz[nt * 16 + fr][k0 + kg];
                bf[nt] = *(const bf16x8*)&Tf[nt * 16 + fr][k0 + kg];
            }
#pragma unroll
            for (int nt = 0; nt < 4; ++nt) {
                az[nt]  = __builtin_amdgcn_mfma_f32_16x16x32_bf16(wz, bz[nt], az[nt], 0, 0, 0);
                afc[nt] = __builtin_amdgcn_mfma_f32_16x16x32_bf16(wf, bf[nt], afc[nt], 0, 0, 0);
            }
        }
        int m = mbase + mrow;
        f32x4 bz = *(const f32x4*)&f1b2[m];
        f32x4 bfv = *(const f32x4*)&f2b2[m];
#pragma unroll
        for (int nt = 0; nt < 4; ++nt) {
            int nl = nt * 16 + fr;
            bf16x8 ozf;
#pragma unroll
            for (int r = 0; r < 4; ++r) {
                ozf[2 * r]     = (__bf16)fast_tanh(az[nt][r] + bz[r]);
                ozf[2 * r + 1] = (__bf16)fast_sig(afc[nt][r] + bfv[r]);
            }
            *(bf16x8*)&g_ZF[(size_t)(n0 + nl) * 256 + 2 * m] = ozf;
        }
    }
}

// ---------------- SRU scan: 4-way chunked affine scan -----------------------
// Column (b,w,c): s_t = f_t*s_{t-1} + (1-f_t)*z_t over scan-time t=0..127
// (h = 127-t for c<64, h = t for c>=64). 4 threads/column, 32 steps each.
__global__ __launch_bounds__(256) void k_scan_par()
{
    __shared__ float sA[4][64], sB[4][64], sS[4][64];

    const int bid = blockIdx.x;          // 1024 blocks
    const int bw = bid >> 1;             // (b*128 + w)
    const int cg = bid & 1;              // c-group: 0 -> c 0..63 (reverse)
    const int b = bw >> 7, w = bw & 127;
    const int tid = threadIdx.x;
    const int q = tid >> 6, cl = tid & 63;
    const int c = cg * 64 + cl;
    const bool rev = (cg == 0);
    const size_t colbase = (size_t)(b * kHW) + w;   // pixel at h=0 for this (b,w)

    float zb[32], fb[32];
    float A = 1.f, Bv = 0.f;
#pragma unroll
    for (int i = 0; i < 32; ++i) {
        int t = q * 32 + i;
        int hh = rev ? (127 - t) : t;
        size_t pix = colbase + (size_t)hh * 128;
        bf16x2 v = *(const bf16x2*)&g_ZF[pix * 256 + 2 * c];
        float z = (float)v[0], f = (float)v[1];
        zb[i] = z; fb[i] = f;
        A = f * A;
        Bv = f * Bv + (1.f - f) * z;
    }
    sA[q][cl] = A;
    sB[q][cl] = Bv;
    __syncthreads();

    if (q == 0) {   // per-column 4-step prefix of incoming states
        float S = 0.f;
#pragma unroll
        for (int j = 0; j < 4; ++j) {
            sS[j][cl] = S;
            S = sA[j][cl] * S + sB[j][cl];
        }
    }
    __syncthreads();

    float st = sS[q][cl];
#pragma unroll
    for (int i = 0; i < 32; ++i) {
        int t = q * 32 + i;
        int hh = rev ? (127 - t) : t;
        size_t pix = colbase + (size_t)hh * 128;
        st = fb[i] * st + (1.f - fb[i]) * zb[i];
        g_S[pix * 128 + c] = (__bf16)fast_sig(st);
    }
}

// ---------------- mega: pmul -> q -> final (512 thr; no Bt staging) ---------
__global__ __launch_bounds__(512) void k_mega(
    const float* __restrict__ pb3, const float* __restrict__ pb1,
    const float* __restrict__ pb2, float* __restrict__ out)
{
    __shared__ __align__(16) char U[33792];   // Pt[64][136]; Qt[64][264] aliases
    auto Pt = (__bf16 (*)[136])U;
    auto Qt = (__bf16 (*)[264])U;

    const int tid = threadIdx.x;
    const int n0 = blockIdx.x * 64;
    const int b = n0 >> 14, hw0 = n0 & 16383;
    const int lane = tid & 63, wid = tid >> 6;   // wid 0..7
    const int fr = lane & 15, kg = (lane >> 4) << 3, mrow = (lane >> 4) << 2;
    const int mbase = wid * 16;

    // ---- gemm0: p = (W3.y1 + pb3)*y1 + y1 -> Pt (y1 fragments from L2) ----
    {
        f32x4 acc[4];
#pragma unroll
        for (int nt = 0; nt < 4; ++nt)
#pragma unroll
            for (int r = 0; r < 4; ++r) acc[nt][r] = 0.f;
#pragma unroll
        for (int k0 = 0; k0 < 128; k0 += 32) {
            bf16x8 af = *(const bf16x8*)&g_w[155648 + (size_t)(mbase + fr) * 128 + k0 + kg];
            bf16x8 bfr[4];
#pragma unroll
            for (int nt = 0; nt < 4; ++nt)
                bfr[nt] = *(const bf16x8*)&g_y1[(size_t)(n0 + nt * 16 + fr) * 128 + k0 + kg];
#pragma unroll
            for (int nt = 0; nt < 4; ++nt)
                acc[nt] = __builtin_amdgcn_mfma_f32_16x16x32_bf16(af, bfr[nt], acc[nt], 0, 0, 0);
        }
        int m = mbase + mrow;
        f32x4 b3 = *(const f32x4*)&pb3[m];
#pragma unroll
        for (int nt = 0; nt < 4; ++nt) {
            int nl = nt * 16 + fr;
            bf16x4 yv = *(const bf16x4*)&g_y1[(size_t)(n0 + nl) * 128 + m];
            bf16x4 o;
#pragma unroll
            for (int r = 0; r < 4; ++r) {
                float y = (float)yv[r];
                o[r] = (__bf16)((acc[nt][r] + b3[r]) * y + y);
            }
            *(bf16x4*)&Pt[nl][m] = o;
        }
    }
    __syncthreads();

    // ---- gemm2: q = gelu(W1[256][128].p + pb1) -> Qt (aliases Pt) ----
    {
        f32x4 acc[2][4];   // [mh][nt]
#pragma unroll
        for (int mh = 0; mh < 2; ++mh)
#pragma unroll
            for (int nt = 0; nt < 4; ++nt)
#pragma unroll
                for (int r = 0; r < 4; ++r) acc[mh][nt][r] = 0.f;
#pragma unroll
        for (int mh = 0; mh < 2; ++mh) {
#pragma unroll
            for (int k0 = 0; k0 < 128; k0 += 32) {
                bf16x8 af = *(const bf16x8*)&g_w[65536 + (size_t)(mh * 128 + mbase + fr) * 128 + k0 + kg];
                bf16x8 bfr[4];
#pragma unroll
                for (int nt = 0; nt < 4; ++nt)
                    bfr[nt] = *(const bf16x8*)&Pt[nt * 16 + fr][k0 + kg];
#pragma unroll
                for (int nt = 0; nt < 4; ++nt)
                    acc[mh][nt] = __builtin_amdgcn_mfma_f32_16x16x32_bf16(af, bfr[nt], acc[mh][nt], 0, 0, 0);
            }
        }
        __syncthreads();   // all Pt reads done -> safe to overwrite as Qt
#pragma unroll
        for (int mh = 0; mh < 2; ++mh) {
            int m = mh * 128 + mbase + mrow;
            f32x4 b1 = *(const f32x4*)&pb1[m];
#pragma unroll
            for (int nt = 0; nt < 4; ++nt) {
                int nl = nt * 16 + fr;
                bf16x4 o;
#pragma unroll
                for (int r = 0; r < 4; ++r)
                    o[r] = (__bf16)fast_gelu(acc[mh][nt][r] + b1[r]);
                *(bf16x4*)&Qt[nl][m] = o;
            }
        }
    }
    __syncthreads();

    // ---- gemm3: out = W2[128][256].q + pb2 + y1*sig  (NCHW f32 store) ----
    {
        f32x4 acc[4];
#pragma unroll
        for (int nt = 0; nt < 4; ++nt)
#pragma unroll
            for (int r = 0; r < 4; ++r) acc[nt][r] = 0.f;
#pragma unroll
        for (int k0 = 0; k0 < 256; k0 += 32) {
            bf16x8 af = *(const bf16x8*)&g_w[98304 + (size_t)(mbase + fr) * 256 + k0 + kg];
            bf16x8 bfr[4];
#pragma unroll
            for (int nt = 0; nt < 4; ++nt)
                bfr[nt] = *(const bf16x8*)&Qt[nt * 16 + fr][k0 + kg];
#pragma unroll
            for (int nt = 0; nt < 4; ++nt)
                acc[nt] = __builtin_amdgcn_mfma_f32_16x16x32_bf16(af, bfr[nt], acc[nt], 0, 0, 0);
        }
        int m = mbase + mrow;
        f32x4 b2 = *(const f32x4*)&pb2[m];
#pragma unroll
        for (int nt = 0; nt < 4; ++nt) {
            int hw = hw0 + nt * 16 + fr;
            size_t pbase = (size_t)(n0 + nt * 16 + fr) * 128;
            bf16x4 yv = *(const bf16x4*)&g_y1[pbase + m];
            bf16x4 sv = *(const bf16x4*)&g_S[pbase + m];
#pragma unroll
            for (int r = 0; r < 4; ++r) {
                out[(size_t)(b * 128 + m + r) * kHW + hw] =
                    acc[nt][r] + b2[r] + (float)yv[r] * (float)sv[r];
            }
        }
    }
}

// ---------------------------------------------------------------------------
extern "C" void kernel_launch(void* const* d_in, const int* in_sizes, int n_in,
                              void* d_out, int out_size, void* d_ws, size_t ws_size,
                              hipStream_t stream)
{
    const float* x    = (const float*)d_in[0];
    const float* d1w  = (const float*)d_in[1];
    const float* d1b  = (const float*)d_in[2];
    const float* d4w  = (const float*)d_in[3];
    const float* d4b  = (const float*)d_in[4];
    const float* pa   = (const float*)d_in[5];
    const float* f1w1 = (const float*)d_in[6];
    const float* f1b1 = (const float*)d_in[7];
    const float* f1w2 = (const float*)d_in[8];
    const float* f1b2 = (const float*)d_in[9];
    const float* f2w1 = (const float*)d_in[10];
    const float* f2b1 = (const float*)d_in[11];
    const float* f2w2 = (const float*)d_in[12];
    const float* f2b2 = (const float*)d_in[13];
    const float* pw1  = (const float*)d_in[14];
    const float* pb1  = (const float*)d_in[15];
    const float* pw2  = (const float*)d_in[16];
    const float* pb2  = (const float*)d_in[17];
    const float* pw3  = (const float*)d_in[18];
    const float* pb3  = (const float*)d_in[19];
    float* out = (float*)d_out;

    k_prepw<<<672, 256, 0, stream>>>(f1w1, f1w2, f2w1, f2w2, pw1, pw2, d1w, d4w, pw3);
    k_fused<<<1024, 512, 0, stream>>>(x, d1b, d4b, pa, f1b1, f1b2, f2b1, f2b2);
    k_scan_par<<<1024, 256, 0, stream>>>();
    k_mega<<<1024, 512, 0, stream>>>(pb3, pb1, pb2, out);

    (void)in_sizes; (void)n_in; (void)d_ws; (void)ws_size; (void)out_size;
}

// Round 21
// 91.286 us; speedup vs baseline: 1.1526x; 1.1526x over previous
//
#include <hip/hip_runtime.h>

// MSSFM round 21 — r20 with the launch-grid bug fixed: k_scan_par needs
// EXACTLY 1024 blocks (4b x 128w x 2 c-groups, 64 cols/block); r20 launched
// 2048 -> blocks 1024+ computed b in [4,8) -> OOB on g_ZF/g_S -> core dump.
// Content: r18 k_mega (Bt staging, 512 thr) + r19 k_scan_par (4-way affine).
// HARD RULE: static LDS <= 64KB. exp INTRINSICS segfault this clang (r8/r9)
// — hardware exp2/rcp via inline asm (r13-validated).

typedef __bf16 bf16x8 __attribute__((ext_vector_type(8)));
typedef __bf16 bf16x4 __attribute__((ext_vector_type(4)));
typedef __bf16 bf16x2 __attribute__((ext_vector_type(2)));
typedef float  f32x4  __attribute__((ext_vector_type(4)));

constexpr int kHW = 16384;   // 128*128

__device__ __align__(16) __bf16 g_y1[8388608];    // NHWC bf16
__device__ __align__(16) __bf16 g_ZF[16777216];   // [pixel][2c]={Z,F}
__device__ __align__(16) __bf16 g_S [8388608];    // sigmoid(y2), NHWC
// g_w: f1w1@0 f1w2@16384 f2w1@32768 f2w2@49152 pw1@65536 pw2@98304
//      A1@131072[128][96] A4@143360[128][96] pw3@155648
__device__ __align__(16) __bf16 g_w [172032];

__device__ __forceinline__ float hw_exp2(float x)
{
    float r;
    asm("v_exp_f32 %0, %1" : "=v"(r) : "v"(x));
    return r;
}
__device__ __forceinline__ float hw_rcp(float x)
{
    float r;
    asm("v_rcp_f32 %0, %1" : "=v"(r) : "v"(x));
    return r;
}
__device__ __forceinline__ float fast_tanh(float x)
{
    return 1.f - 2.f * hw_rcp(hw_exp2(2.88539008f * x) + 1.f);
}
__device__ __forceinline__ float fast_sig(float x)
{
    return hw_rcp(1.f + hw_exp2(-1.44269504f * x));
}
__device__ __forceinline__ float fast_gelu(float x)
{
    return 0.5f * x * (1.f + fast_tanh(0.79788456f * (x + 0.044715f * x * x * x)));
}

// ---------------- pack weights to bf16 --------------------------------------
__global__ __launch_bounds__(256) void k_prepw(
    const float* __restrict__ f1w1, const float* __restrict__ f1w2,
    const float* __restrict__ f2w1, const float* __restrict__ f2w2,
    const float* __restrict__ pw1, const float* __restrict__ pw2,
    const float* __restrict__ d1w, const float* __restrict__ d4w,
    const float* __restrict__ pw3)
{
    int idx = blockIdx.x * 256 + threadIdx.x;  // 172032
    float v;
    if (idx < 16384)        v = f1w1[idx];
    else if (idx < 32768)   v = f1w2[idx - 16384];
    else if (idx < 49152)   v = f2w1[idx - 32768];
    else if (idx < 65536)   v = f2w2[idx - 49152];
    else if (idx < 98304)   v = pw1[idx - 65536];
    else if (idx < 131072)  v = pw2[idx - 98304];
    else if (idx < 155648) {
        // A1/A4: [128 c][96 k], k = tap*8+s (tap=kh*3+kw), taps 9..11 zero
        int r = idx - 131072;
        const float* src = d1w;
        if (r >= 12288) { r -= 12288; src = d4w; }
        int c = r / 96, k = r - c * 96;
        int tap = k >> 3, s = k & 7;
        v = (tap < 9) ? src[c * 72 + s * 9 + tap] : 0.f;
    } else                  v = pw3[idx - 155648];
    g_w[idx] = (__bf16)v;
}

// ---------------- fused: DPB conv + dual-branch prescan (512 thr) -----------
__global__ __launch_bounds__(512) void k_fused(
    const float* __restrict__ x, const float* __restrict__ d1b,
    const float* __restrict__ d4b, const float* __restrict__ pa,
    const float* __restrict__ f1b1, const float* __restrict__ f1b2,
    const float* __restrict__ f2b1, const float* __restrict__ f2b2)
{
    __shared__ __align__(16) char U1[17408];   // Bt[64][136], then Tz[64][136]
    __shared__ __align__(16) char U2[17408];   // patch[5][80][8], then Tf[64][136]
    auto Bt    = (__bf16 (*)[136])U1;
    auto Tz    = (__bf16 (*)[136])U1;
    auto patch = (__bf16 (*)[80][8])U2;
    auto Tf    = (__bf16 (*)[136])U2;

    const int tid = threadIdx.x;
    const int n0 = blockIdx.x * 64;            // global pixel base
    const int b = n0 >> 14, hw0 = n0 & 16383;
    const int h = hw0 >> 7, w0 = hw0 & 127;

    // ---- stage x patch: rows {h-7,h-1,h,h+1,h+7} x cols [w0-7, w0+70] ------
    const int roff[5] = {-7, -1, 0, 1, 7};
    if (tid < 400) {
        int rs = tid / 80, c = tid - rs * 80;
        int row = h + roff[rs], wc = w0 + c - 7;
        bf16x8 v;
#pragma unroll
        for (int s = 0; s < 8; ++s) v[s] = (__bf16)0.f;
        if ((unsigned)row < 128u && (unsigned)wc < 128u && c < 78) {
#pragma unroll
            for (int s = 0; s < 8; ++s)
                v[s] = (__bf16)x[(size_t)(b * 8 + s) * kHW + row * 128 + wc];
        }
        *(bf16x8*)&patch[rs][c][0] = v;
    }

    const int lane = tid & 63, wid = tid >> 6;   // wid 0..7, 16-row M slice
    const int fr = lane & 15, kg = (lane >> 4) << 3, mrow = (lane >> 4) << 2;
    const int mbase = wid * 16;

    f32x4 acc1[4], acc4[4];
#pragma unroll
    for (int nt = 0; nt < 4; ++nt)
#pragma unroll
        for (int r = 0; r < 4; ++r) { acc1[nt][r] = 0.f; acc4[nt][r] = 0.f; }

    __syncthreads();   // patch ready

#pragma unroll
    for (int cv = 0; cv < 2; ++cv) {
        const __bf16* Ag = g_w + (cv ? 143360 : 131072);
#pragma unroll
        for (int k0 = 0; k0 < 96; k0 += 32) {
            bf16x8 af = *(const bf16x8*)&Ag[(size_t)(mbase + fr) * 96 + k0 + kg];
            int tap = (k0 + kg) >> 3;   // uniform within a 16-lane group
            bf16x8 bfr[4];
#pragma unroll
            for (int nt = 0; nt < 4; ++nt) {
                bf16x8 bv;
#pragma unroll
                for (int i = 0; i < 8; ++i) bv[i] = (__bf16)0.f;
                if (tap < 9) {
                    int dh = tap / 3 - 1, dw = tap % 3 - 1;
                    int rowsel = cv ? (dh + 1) * 2 : dh + 2;
                    int col = nt * 16 + fr + dw * (cv ? 7 : 1) + 7;
                    bv = *(const bf16x8*)&patch[rowsel][col][0];
                }
                bfr[nt] = bv;
            }
            if (cv == 0) {
#pragma unroll
                for (int nt = 0; nt < 4; ++nt)
                    acc1[nt] = __builtin_amdgcn_mfma_f32_16x16x32_bf16(af, bfr[nt], acc1[nt], 0, 0, 0);
            } else {
#pragma unroll
                for (int nt = 0; nt < 4; ++nt)
                    acc4[nt] = __builtin_amdgcn_mfma_f32_16x16x32_bf16(af, bfr[nt], acc4[nt], 0, 0, 0);
            }
        }
    }

    __syncthreads();

    // ---- epilogue: y1 = prelu + prelu -> Bt (LDS, U1) + g_y1 (NHWC) ----
    const float pav = pa[0];
    {
        int m = mbase + mrow;
        f32x4 b1v = *(const f32x4*)&d1b[m];
        f32x4 b4v = *(const f32x4*)&d4b[m];
#pragma unroll
        for (int nt = 0; nt < 4; ++nt) {
            int nl = nt * 16 + fr;
            bf16x4 o;
#pragma unroll
            for (int r = 0; r < 4; ++r) {
                float v1 = acc1[nt][r] + b1v[r];
                float v4 = acc4[nt][r] + b4v[r];
                v1 = (v1 >= 0.f) ? v1 : pav * v1;
                v4 = (v4 >= 0.f) ? v4 : pav * v4;
                o[r] = (__bf16)(v1 + v4);
            }
            *(bf16x4*)&Bt[nl][m] = o;
            *(bf16x4*)&g_y1[(size_t)(n0 + nl) * 128 + m] = o;
        }
    }
    __syncthreads();   // Bt fully written; patch dead

    // ---- prescan phase 1 (dual): t1 = tanh(W11.y1+b), t2 = tanh(W21.y1+b) --
    {
        f32x4 az[4], afc[4];
#pragma unroll
        for (int nt = 0; nt < 4; ++nt)
#pragma unroll
            for (int r = 0; r < 4; ++r) { az[nt][r] = 0.f; afc[nt][r] = 0.f; }
#pragma unroll
        for (int k0 = 0; k0 < 128; k0 += 32) {
            size_t rowoff = (size_t)(mbase + fr) * 128 + k0 + kg;
            bf16x8 wz = *(const bf16x8*)&g_w[rowoff];            // f1w1
            bf16x8 wf = *(const bf16x8*)&g_w[32768 + rowoff];    // f2w1
            bf16x8 bfr[4];
#pragma unroll
            for (int nt = 0; nt < 4; ++nt)
                bfr[nt] = *(const bf16x8*)&Bt[nt * 16 + fr][k0 + kg];
#pragma unroll
            for (int nt = 0; nt < 4; ++nt) {
                az[nt]  = __builtin_amdgcn_mfma_f32_16x16x32_bf16(wz, bfr[nt], az[nt], 0, 0, 0);
                afc[nt] = __builtin_amdgcn_mfma_f32_16x16x32_bf16(wf, bfr[nt], afc[nt], 0, 0, 0);
            }
        }
        __syncthreads();   // ALL Bt reads complete -> Tz may overwrite U1
        int m = mbase + mrow;
        f32x4 bz = *(const f32x4*)&f1b1[m];
        f32x4 bfv = *(const f32x4*)&f2b1[m];
#pragma unroll
        for (int nt = 0; nt < 4; ++nt) {
            int nl = nt * 16 + fr;
            bf16x4 oz, of;
#pragma unroll
            for (int r = 0; r < 4; ++r) {
                oz[r] = (__bf16)fast_tanh(az[nt][r] + bz[r]);
                of[r] = (__bf16)fast_tanh(afc[nt][r] + bfv[r]);
            }
            *(bf16x4*)&Tz[nl][m] = oz;
            *(bf16x4*)&Tf[nl][m] = of;
        }
    }
    __syncthreads();   // Tz/Tf ready

    // ---- prescan phase 2 (dual): Z = tanh(W12.t1+b), F = sig(W22.t2+b) -----
    {
        f32x4 az[4], afc[4];
#pragma unroll
        for (int nt = 0; nt < 4; ++nt)
#pragma unroll
            for (int r = 0; r < 4; ++r) { az[nt][r] = 0.f; afc[nt][r] = 0.f; }
#pragma unroll
        for (int k0 = 0; k0 < 128; k0 += 32) {
            size_t rowoff = (size_t)(mbase + fr) * 128 + k0 + kg;
            bf16x8 wz = *(const bf16x8*)&g_w[16384 + rowoff];    // f1w2
            bf16x8 wf = *(const bf16x8*)&g_w[49152 + rowoff];    // f2w2
            bf16x8 bz[4], bf[4];
#pragma unroll
            for (int nt = 0; nt < 4; ++nt) {
                bz[nt] = *(const bf16x8*)&Tz[nt * 16 + fr][k0 + kg];
                bf[nt] = *(const bf16x8*)&Tf[nt * 16 + fr][k0 + kg];
            }
#pragma unroll
            for (int nt = 0; nt < 4; ++nt) {
                az[nt]  = __builtin_amdgcn_mfma_f32_16x16x32_bf16(wz, bz[nt], az[nt], 0, 0, 0);
                afc[nt] = __builtin_amdgcn_mfma_f32_16x16x32_bf16(wf, bf[nt], afc[nt], 0, 0, 0);
            }
        }
        int m = mbase + mrow;
        f32x4 bz = *(const f32x4*)&f1b2[m];
        f32x4 bfv = *(const f32x4*)&f2b2[m];
#pragma unroll
        for (int nt = 0; nt < 4; ++nt) {
            int nl = nt * 16 + fr;
            bf16x8 ozf;
#pragma unroll
            for (int r = 0; r < 4; ++r) {
                ozf[2 * r]     = (__bf16)fast_tanh(az[nt][r] + bz[r]);
                ozf[2 * r + 1] = (__bf16)fast_sig(afc[nt][r] + bfv[r]);
            }
            *(bf16x8*)&g_ZF[(size_t)(n0 + nl) * 256 + 2 * m] = ozf;
        }
    }
}

// ---------------- SRU scan: 4-way chunked affine scan (1024 blocks!) --------
// Covers 4b x 128w x 2 c-groups = 1024 blocks, 64 columns x 4 chunks each.
__global__ __launch_bounds__(256) void k_scan_par()
{
    __shared__ float sA[4][64], sB[4][64], sS[4][64];

    const int bid = blockIdx.x;          // MUST be 1024 blocks
    const int bw = bid >> 1;             // (b*128 + w), 0..511
    const int cg = bid & 1;              // 0 -> c 0..63 (reverse scan)
    const int b = bw >> 7, w = bw & 127;
    const int tid = threadIdx.x;
    const int q = tid >> 6, cl = tid & 63;
    const int c = cg * 64 + cl;
    const bool rev = (cg == 0);
    const size_t colbase = (size_t)(b * kHW) + w;

    float zb[32], fb[32];
    float A = 1.f, Bv = 0.f;
#pragma unroll
    for (int i = 0; i < 32; ++i) {
        int t = q * 32 + i;
        int hh = rev ? (127 - t) : t;
        size_t pix = colbase + (size_t)hh * 128;
        bf16x2 v = *(const bf16x2*)&g_ZF[pix * 256 + 2 * c];
        float z = (float)v[0], f = (float)v[1];
        zb[i] = z; fb[i] = f;
        A = f * A;
        Bv = f * Bv + (1.f - f) * z;
    }
    sA[q][cl] = A;
    sB[q][cl] = Bv;
    __syncthreads();

    if (q == 0) {
        float S = 0.f;
#pragma unroll
        for (int j = 0; j < 4; ++j) {
            sS[j][cl] = S;
            S = sA[j][cl] * S + sB[j][cl];
        }
    }
    __syncthreads();

    float st = sS[q][cl];
#pragma unroll
    for (int i = 0; i < 32; ++i) {
        int t = q * 32 + i;
        int hh = rev ? (127 - t) : t;
        size_t pix = colbase + (size_t)hh * 128;
        st = fb[i] * st + (1.f - fb[i]) * zb[i];
        g_S[pix * 128 + c] = (__bf16)fast_sig(st);
    }
}

// ---------------- mega: pmul -> q -> final (512 thr, r18 version) -----------
__global__ __launch_bounds__(512) void k_mega(
    const float* __restrict__ pb3, const float* __restrict__ pb1,
    const float* __restrict__ pb2, float* __restrict__ out)
{
    __shared__ __align__(16) char U[34816];   // Bt | Pt ; Qt aliases both
    auto Bt = (__bf16 (*)[136])U;
    auto Pt = (__bf16 (*)[136])(U + 17408);
    auto Qt = (__bf16 (*)[264])U;

    const int tid = threadIdx.x;
    const int n0 = blockIdx.x * 64;
    const int b = n0 >> 14, hw0 = n0 & 16383;
    const int lane = tid & 63, wid = tid >> 6;   // wid 0..7
    const int fr = lane & 15, kg = (lane >> 4) << 3, mrow = (lane >> 4) << 2;
    const int mbase = wid * 16;

    // stage y1 tile (NHWC bf16, coalesced): 16 bf16 per thread
    {
        int n = tid >> 3, ks = (tid & 7) * 16;
        const __bf16* src = g_y1 + (size_t)(n0 + n) * 128 + ks;
        *(bf16x8*)&Bt[n][ks]     = *(const bf16x8*)src;
        *(bf16x8*)&Bt[n][ks + 8] = *(const bf16x8*)(src + 8);
    }
    __syncthreads();

    // ---- gemm0: p = (W3.y1 + pb3)*y1 + y1 -> Pt ----
    {
        f32x4 acc[4];
#pragma unroll
        for (int nt = 0; nt < 4; ++nt)
#pragma unroll
            for (int r = 0; r < 4; ++r) acc[nt][r] = 0.f;
#pragma unroll
        for (int k0 = 0; k0 < 128; k0 += 32) {
            bf16x8 af = *(const bf16x8*)&g_w[155648 + (size_t)(mbase + fr) * 128 + k0 + kg];
            bf16x8 bfr[4];
#pragma unroll
            for (int nt = 0; nt < 4; ++nt)
                bfr[nt] = *(const bf16x8*)&Bt[nt * 16 + fr][k0 + kg];
#pragma unroll
            for (int nt = 0; nt < 4; ++nt)
                acc[nt] = __builtin_amdgcn_mfma_f32_16x16x32_bf16(af, bfr[nt], acc[nt], 0, 0, 0);
        }
        int m = mbase + mrow;
        f32x4 b3 = *(const f32x4*)&pb3[m];
#pragma unroll
        for (int nt = 0; nt < 4; ++nt) {
            int nl = nt * 16 + fr;
            bf16x4 yv = *(const bf16x4*)&Bt[nl][m];
            bf16x4 o;
#pragma unroll
            for (int r = 0; r < 4; ++r) {
                float y = (float)yv[r];
                o[r] = (__bf16)((acc[nt][r] + b3[r]) * y + y);
            }
            *(bf16x4*)&Pt[nl][m] = o;
        }
    }
    __syncthreads();

    // ---- gemm2: q = gelu(W1[256][128].p + pb1) -> Qt (aliases Bt+Pt) ----
    {
        f32x4 acc[2][4];   // [mh][nt]
#pragma unroll
        for (int mh = 0; mh < 2; ++mh)
#pragma unroll
            for (int nt = 0; nt < 4; ++nt)
#pragma unroll
                for (int r = 0; r < 4; ++r) acc[mh][nt][r] = 0.f;
#pragma unroll
        for (int mh = 0; mh < 2; ++mh) {
#pragma unroll
            for (int k0 = 0; k0 < 128; k0 += 32) {
                bf16x8 af = *(const bf16x8*)&g_w[65536 + (size_t)(mh * 128 + mbase + fr) * 128 + k0 + kg];
                bf16x8 bfr[4];
#pragma unroll
                for (int nt = 0; nt < 4; ++nt)
                    bfr[nt] = *(const bf16x8*)&Pt[nt * 16 + fr][k0 + kg];
#pragma unroll
                for (int nt = 0; nt < 4; ++nt)
                    acc[mh][nt] = __builtin_amdgcn_mfma_f32_16x16x32_bf16(af, bfr[nt], acc[mh][nt], 0, 0, 0);
            }
        }
        __syncthreads();   // all Pt reads done -> safe to overwrite as Qt
#pragma unroll
        for (int mh = 0; mh < 2; ++mh) {
            int m = mh * 128 + mbase + mrow;
            f32x4 b1 = *(const f32x4*)&pb1[m];
#pragma unroll
            for (int nt = 0; nt < 4; ++nt) {
                int nl = nt * 16 + fr;
                bf16x4 o;
#pragma unroll
                for (int r = 0; r < 4; ++r)
                    o[r] = (__bf16)fast_gelu(acc[mh][nt][r] + b1[r]);
                *(bf16x4*)&Qt[nl][m] = o;
            }
        }
    }
    __syncthreads();

    // ---- gemm3: out = W2[128][256].q + pb2 + y1*sig  (NCHW f32 store) ----
    {
        f32x4 acc[4];
#pragma unroll
        for (int nt = 0; nt < 4; ++nt)
#pragma unroll
            for (int r = 0; r < 4; ++r) acc[nt][r] = 0.f;
#pragma unroll
        for (int k0 = 0; k0 < 256; k0 += 32) {
            bf16x8 af = *(const bf16x8*)&g_w[98304 + (size_t)(mbase + fr) * 256 + k0 + kg];
            bf16x8 bfr[4];
#pragma unroll
            for (int nt = 0; nt < 4; ++nt)
                bfr[nt] = *(const bf16x8*)&Qt[nt * 16 + fr][k0 + kg];
#pragma unroll
            for (int nt = 0; nt < 4; ++nt)
                acc[nt] = __builtin_amdgcn_mfma_f32_16x16x32_bf16(af, bfr[nt], acc[nt], 0, 0, 0);
        }
        int m = mbase + mrow;
        f32x4 b2 = *(const f32x4*)&pb2[m];
#pragma unroll
        for (int nt = 0; nt < 4; ++nt) {
            int hw = hw0 + nt * 16 + fr;
            size_t pbase = (size_t)(n0 + nt * 16 + fr) * 128;
            bf16x4 yv = *(const bf16x4*)&g_y1[pbase + m];
            bf16x4 sv = *(const bf16x4*)&g_S[pbase + m];
#pragma unroll
            for (int r = 0; r < 4; ++r) {
                out[(size_t)(b * 128 + m + r) * kHW + hw] =
                    acc[nt][r] + b2[r] + (float)yv[r] * (float)sv[r];
            }
        }
    }
}

// ---------------------------------------------------------------------------
extern "C" void kernel_launch(void* const* d_in, const int* in_sizes, int n_in,
                              void* d_out, int out_size, void* d_ws, size_t ws_size,
                              hipStream_t stream)
{
    const float* x    = (const float*)d_in[0];
    const float* d1w  = (const float*)d_in[1];
    const float* d1b  = (const float*)d_in[2];
    const float* d4w  = (const float*)d_in[3];
    const float* d4b  = (const float*)d_in[4];
    const float* pa   = (const float*)d_in[5];
    const float* f1w1 = (const float*)d_in[6];
    const float* f1b1 = (const float*)d_in[7];
    const float* f1w2 = (const float*)d_in[8];
    const float* f1b2 = (const float*)d_in[9];
    const float* f2w1 = (const float*)d_in[10];
    const float* f2b1 = (const float*)d_in[11];
    const float* f2w2 = (const float*)d_in[12];
    const float* f2b2 = (const float*)d_in[13];
    const float* pw1  = (const float*)d_in[14];
    const float* pb1  = (const float*)d_in[15];
    const float* pw2  = (const float*)d_in[16];
    const float* pb2  = (const float*)d_in[17];
    const float* pw3  = (const float*)d_in[18];
    const float* pb3  = (const float*)d_in[19];
    float* out = (float*)d_out;

    k_prepw<<<672, 256, 0, stream>>>(f1w1, f1w2, f2w1, f2w2, pw1, pw2, d1w, d4w, pw3);
    k_fused<<<1024, 512, 0, stream>>>(x, d1b, d4b, pa, f1b1, f1b2, f2b1, f2b2);
    k_scan_par<<<1024, 256, 0, stream>>>();
    k_mega<<<1024, 512, 0, stream>>>(pb3, pb1, pb2, out);

    (void)in_sizes; (void)n_in; (void)d_ws; (void)ws_size; (void)out_size;
}

// Round 22
// 90.027 us; speedup vs baseline: 1.1687x; 1.0140x over previous
//
#include <hip/hip_runtime.h>

// MSSFM round 22 — r21 (91.3us, PASS) + two critical-path cuts:
//   1. k_fused: redundant post-conv __syncthreads() removed (patch's last
//      read precedes Tf's first write by 2 other barriers).
//   2. k_mega gemm2: k-outer restructure — Pt fragments loaded ONCE per
//      k-step for both mh halves (was twice); 8 independent MFMAs/step.
//      VGPR 52 -> ~60, still <=64 -> 32 waves/CU retained.
// HARD RULE: static LDS <= 64KB. exp INTRINSICS segfault this clang (r8/r9)
// — hardware exp2/rcp via inline asm (r13-validated).
// k_scan_par MUST launch with exactly 1024 blocks (r20 lesson).

typedef __bf16 bf16x8 __attribute__((ext_vector_type(8)));
typedef __bf16 bf16x4 __attribute__((ext_vector_type(4)));
typedef __bf16 bf16x2 __attribute__((ext_vector_type(2)));
typedef float  f32x4  __attribute__((ext_vector_type(4)));

constexpr int kHW = 16384;   // 128*128

__device__ __align__(16) __bf16 g_y1[8388608];    // NHWC bf16
__device__ __align__(16) __bf16 g_ZF[16777216];   // [pixel][2c]={Z,F}
__device__ __align__(16) __bf16 g_S [8388608];    // sigmoid(y2), NHWC
// g_w: f1w1@0 f1w2@16384 f2w1@32768 f2w2@49152 pw1@65536 pw2@98304
//      A1@131072[128][96] A4@143360[128][96] pw3@155648
__device__ __align__(16) __bf16 g_w [172032];

__device__ __forceinline__ float hw_exp2(float x)
{
    float r;
    asm("v_exp_f32 %0, %1" : "=v"(r) : "v"(x));
    return r;
}
__device__ __forceinline__ float hw_rcp(float x)
{
    float r;
    asm("v_rcp_f32 %0, %1" : "=v"(r) : "v"(x));
    return r;
}
__device__ __forceinline__ float fast_tanh(float x)
{
    return 1.f - 2.f * hw_rcp(hw_exp2(2.88539008f * x) + 1.f);
}
__device__ __forceinline__ float fast_sig(float x)
{
    return hw_rcp(1.f + hw_exp2(-1.44269504f * x));
}
__device__ __forceinline__ float fast_gelu(float x)
{
    return 0.5f * x * (1.f + fast_tanh(0.79788456f * (x + 0.044715f * x * x * x)));
}

// ---------------- pack weights to bf16 --------------------------------------
__global__ __launch_bounds__(256) void k_prepw(
    const float* __restrict__ f1w1, const float* __restrict__ f1w2,
    const float* __restrict__ f2w1, const float* __restrict__ f2w2,
    const float* __restrict__ pw1, const float* __restrict__ pw2,
    const float* __restrict__ d1w, const float* __restrict__ d4w,
    const float* __restrict__ pw3)
{
    int idx = blockIdx.x * 256 + threadIdx.x;  // 172032
    float v;
    if (idx < 16384)        v = f1w1[idx];
    else if (idx < 32768)   v = f1w2[idx - 16384];
    else if (idx < 49152)   v = f2w1[idx - 32768];
    else if (idx < 65536)   v = f2w2[idx - 49152];
    else if (idx < 98304)   v = pw1[idx - 65536];
    else if (idx < 131072)  v = pw2[idx - 98304];
    else if (idx < 155648) {
        // A1/A4: [128 c][96 k], k = tap*8+s (tap=kh*3+kw), taps 9..11 zero
        int r = idx - 131072;
        const float* src = d1w;
        if (r >= 12288) { r -= 12288; src = d4w; }
        int c = r / 96, k = r - c * 96;
        int tap = k >> 3, s = k & 7;
        v = (tap < 9) ? src[c * 72 + s * 9 + tap] : 0.f;
    } else                  v = pw3[idx - 155648];
    g_w[idx] = (__bf16)v;
}

// ---------------- fused: DPB conv + dual-branch prescan (512 thr) -----------
__global__ __launch_bounds__(512) void k_fused(
    const float* __restrict__ x, const float* __restrict__ d1b,
    const float* __restrict__ d4b, const float* __restrict__ pa,
    const float* __restrict__ f1b1, const float* __restrict__ f1b2,
    const float* __restrict__ f2b1, const float* __restrict__ f2b2)
{
    __shared__ __align__(16) char U1[17408];   // Bt[64][136], then Tz[64][136]
    __shared__ __align__(16) char U2[17408];   // patch[5][80][8], then Tf[64][136]
    auto Bt    = (__bf16 (*)[136])U1;
    auto Tz    = (__bf16 (*)[136])U1;
    auto patch = (__bf16 (*)[80][8])U2;
    auto Tf    = (__bf16 (*)[136])U2;

    const int tid = threadIdx.x;
    const int n0 = blockIdx.x * 64;            // global pixel base
    const int b = n0 >> 14, hw0 = n0 & 16383;
    const int h = hw0 >> 7, w0 = hw0 & 127;

    // ---- stage x patch: rows {h-7,h-1,h,h+1,h+7} x cols [w0-7, w0+70] ------
    const int roff[5] = {-7, -1, 0, 1, 7};
    if (tid < 400) {
        int rs = tid / 80, c = tid - rs * 80;
        int row = h + roff[rs], wc = w0 + c - 7;
        bf16x8 v;
#pragma unroll
        for (int s = 0; s < 8; ++s) v[s] = (__bf16)0.f;
        if ((unsigned)row < 128u && (unsigned)wc < 128u && c < 78) {
#pragma unroll
            for (int s = 0; s < 8; ++s)
                v[s] = (__bf16)x[(size_t)(b * 8 + s) * kHW + row * 128 + wc];
        }
        *(bf16x8*)&patch[rs][c][0] = v;
    }

    const int lane = tid & 63, wid = tid >> 6;   // wid 0..7, 16-row M slice
    const int fr = lane & 15, kg = (lane >> 4) << 3, mrow = (lane >> 4) << 2;
    const int mbase = wid * 16;

    f32x4 acc1[4], acc4[4];
#pragma unroll
    for (int nt = 0; nt < 4; ++nt)
#pragma unroll
        for (int r = 0; r < 4; ++r) { acc1[nt][r] = 0.f; acc4[nt][r] = 0.f; }

    __syncthreads();   // patch ready

#pragma unroll
    for (int cv = 0; cv < 2; ++cv) {
        const __bf16* Ag = g_w + (cv ? 143360 : 131072);
#pragma unroll
        for (int k0 = 0; k0 < 96; k0 += 32) {
            bf16x8 af = *(const bf16x8*)&Ag[(size_t)(mbase + fr) * 96 + k0 + kg];
            int tap = (k0 + kg) >> 3;   // uniform within a 16-lane group
            bf16x8 bfr[4];
#pragma unroll
            for (int nt = 0; nt < 4; ++nt) {
                bf16x8 bv;
#pragma unroll
                for (int i = 0; i < 8; ++i) bv[i] = (__bf16)0.f;
                if (tap < 9) {
                    int dh = tap / 3 - 1, dw = tap % 3 - 1;
                    int rowsel = cv ? (dh + 1) * 2 : dh + 2;
                    int col = nt * 16 + fr + dw * (cv ? 7 : 1) + 7;
                    bv = *(const bf16x8*)&patch[rowsel][col][0];
                }
                bfr[nt] = bv;
            }
            if (cv == 0) {
#pragma unroll
                for (int nt = 0; nt < 4; ++nt)
                    acc1[nt] = __builtin_amdgcn_mfma_f32_16x16x32_bf16(af, bfr[nt], acc1[nt], 0, 0, 0);
            } else {
#pragma unroll
                for (int nt = 0; nt < 4; ++nt)
                    acc4[nt] = __builtin_amdgcn_mfma_f32_16x16x32_bf16(af, bfr[nt], acc4[nt], 0, 0, 0);
            }
        }
    }

    // NOTE: no barrier here (r22): patch's last read is above; its alias Tf
    // is first written after TWO subsequent barriers. Bt writes below target
    // U1, untouched by conv-phase reads.

    // ---- epilogue: y1 = prelu + prelu -> Bt (LDS, U1) + g_y1 (NHWC) ----
    const float pav = pa[0];
    {
        int m = mbase + mrow;
        f32x4 b1v = *(const f32x4*)&d1b[m];
        f32x4 b4v = *(const f32x4*)&d4b[m];
#pragma unroll
        for (int nt = 0; nt < 4; ++nt) {
            int nl = nt * 16 + fr;
            bf16x4 o;
#pragma unroll
            for (int r = 0; r < 4; ++r) {
                float v1 = acc1[nt][r] + b1v[r];
                float v4 = acc4[nt][r] + b4v[r];
                v1 = (v1 >= 0.f) ? v1 : pav * v1;
                v4 = (v4 >= 0.f) ? v4 : pav * v4;
                o[r] = (__bf16)(v1 + v4);
            }
            *(bf16x4*)&Bt[nl][m] = o;
            *(bf16x4*)&g_y1[(size_t)(n0 + nl) * 128 + m] = o;
        }
    }
    __syncthreads();   // Bt fully written; patch dead

    // ---- prescan phase 1 (dual): t1 = tanh(W11.y1+b), t2 = tanh(W21.y1+b) --
    {
        f32x4 az[4], afc[4];
#pragma unroll
        for (int nt = 0; nt < 4; ++nt)
#pragma unroll
            for (int r = 0; r < 4; ++r) { az[nt][r] = 0.f; afc[nt][r] = 0.f; }
#pragma unroll
        for (int k0 = 0; k0 < 128; k0 += 32) {
            size_t rowoff = (size_t)(mbase + fr) * 128 + k0 + kg;
            bf16x8 wz = *(const bf16x8*)&g_w[rowoff];            // f1w1
            bf16x8 wf = *(const bf16x8*)&g_w[32768 + rowoff];    // f2w1
            bf16x8 bfr[4];
#pragma unroll
            for (int nt = 0; nt < 4; ++nt)
                bfr[nt] = *(const bf16x8*)&Bt[nt * 16 + fr][k0 + kg];
#pragma unroll
            for (int nt = 0; nt < 4; ++nt) {
                az[nt]  = __builtin_amdgcn_mfma_f32_16x16x32_bf16(wz, bfr[nt], az[nt], 0, 0, 0);
                afc[nt] = __builtin_amdgcn_mfma_f32_16x16x32_bf16(wf, bfr[nt], afc[nt], 0, 0, 0);
            }
        }
        __syncthreads();   // ALL Bt reads complete -> Tz may overwrite U1
        int m = mbase + mrow;
        f32x4 bz = *(const f32x4*)&f1b1[m];
        f32x4 bfv = *(const f32x4*)&f2b1[m];
#pragma unroll
        for (int nt = 0; nt < 4; ++nt) {
            int nl = nt * 16 + fr;
            bf16x4 oz, of;
#pragma unroll
            for (int r = 0; r < 4; ++r) {
                oz[r] = (__bf16)fast_tanh(az[nt][r] + bz[r]);
                of[r] = (__bf16)fast_tanh(afc[nt][r] + bfv[r]);
            }
            *(bf16x4*)&Tz[nl][m] = oz;
            *(bf16x4*)&Tf[nl][m] = of;
        }
    }
    __syncthreads();   // Tz/Tf ready

    // ---- prescan phase 2 (dual): Z = tanh(W12.t1+b), F = sig(W22.t2+b) -----
    {
        f32x4 az[4], afc[4];
#pragma unroll
        for (int nt = 0; nt < 4; ++nt)
#pragma unroll
            for (int r = 0; r < 4; ++r) { az[nt][r] = 0.f; afc[nt][r] = 0.f; }
#pragma unroll
        for (int k0 = 0; k0 < 128; k0 += 32) {
            size_t rowoff = (size_t)(mbase + fr) * 128 + k0 + kg;
            bf16x8 wz = *(const bf16x8*)&g_w[16384 + rowoff];    // f1w2
            bf16x8 wf = *(const bf16x8*)&g_w[49152 + rowoff];    // f2w2
            bf16x8 bz[4], bf[4];
#pragma unroll
            for (int nt = 0; nt < 4; ++nt) {
                bz[nt] = *(const bf16x8*)&Tz[nt * 16 + fr][k0 + kg];
                bf[nt] = *(const bf16x8*)&Tf[nt * 16 + fr][k0 + kg];
            }
#pragma unroll
            for (int nt = 0; nt < 4; ++nt) {
                az[nt]  = __builtin_amdgcn_mfma_f32_16x16x32_bf16(wz, bz[nt], az[nt], 0, 0, 0);
                afc[nt] = __builtin_amdgcn_mfma_f32_16x16x32_bf16(wf, bf[nt], afc[nt], 0, 0, 0);
            }
        }
        int m = mbase + mrow;
        f32x4 bz = *(const f32x4*)&f1b2[m];
        f32x4 bfv = *(const f32x4*)&f2b2[m];
#pragma unroll
        for (int nt = 0; nt < 4; ++nt) {
            int nl = nt * 16 + fr;
            bf16x8 ozf;
#pragma unroll
            for (int r = 0; r < 4; ++r) {
                ozf[2 * r]     = (__bf16)fast_tanh(az[nt][r] + bz[r]);
                ozf[2 * r + 1] = (__bf16)fast_sig(afc[nt][r] + bfv[r]);
            }
            *(bf16x8*)&g_ZF[(size_t)(n0 + nl) * 256 + 2 * m] = ozf;
        }
    }
}

// ---------------- SRU scan: 4-way chunked affine scan (1024 blocks!) --------
__global__ __launch_bounds__(256) void k_scan_par()
{
    __shared__ float sA[4][64], sB[4][64], sS[4][64];

    const int bid = blockIdx.x;          // MUST be 1024 blocks
    const int bw = bid >> 1;             // (b*128 + w), 0..511
    const int cg = bid & 1;              // 0 -> c 0..63 (reverse scan)
    const int b = bw >> 7, w = bw & 127;
    const int tid = threadIdx.x;
    const int q = tid >> 6, cl = tid & 63;
    const int c = cg * 64 + cl;
    const bool rev = (cg == 0);
    const size_t colbase = (size_t)(b * kHW) + w;

    float zb[32], fb[32];
    float A = 1.f, Bv = 0.f;
#pragma unroll
    for (int i = 0; i < 32; ++i) {
        int t = q * 32 + i;
        int hh = rev ? (127 - t) : t;
        size_t pix = colbase + (size_t)hh * 128;
        bf16x2 v = *(const bf16x2*)&g_ZF[pix * 256 + 2 * c];
        float z = (float)v[0], f = (float)v[1];
        zb[i] = z; fb[i] = f;
        A = f * A;
        Bv = f * Bv + (1.f - f) * z;
    }
    sA[q][cl] = A;
    sB[q][cl] = Bv;
    __syncthreads();

    if (q == 0) {
        float S = 0.f;
#pragma unroll
        for (int j = 0; j < 4; ++j) {
            sS[j][cl] = S;
            S = sA[j][cl] * S + sB[j][cl];
        }
    }
    __syncthreads();

    float st = sS[q][cl];
#pragma unroll
    for (int i = 0; i < 32; ++i) {
        int t = q * 32 + i;
        int hh = rev ? (127 - t) : t;
        size_t pix = colbase + (size_t)hh * 128;
        st = fb[i] * st + (1.f - fb[i]) * zb[i];
        g_S[pix * 128 + c] = (__bf16)fast_sig(st);
    }
}

// ---------------- mega: pmul -> q -> final (512 thr) ------------------------
__global__ __launch_bounds__(512) void k_mega(
    const float* __restrict__ pb3, const float* __restrict__ pb1,
    const float* __restrict__ pb2, float* __restrict__ out)
{
    __shared__ __align__(16) char U[34816];   // Bt | Pt ; Qt aliases both
    auto Bt = (__bf16 (*)[136])U;
    auto Pt = (__bf16 (*)[136])(U + 17408);
    auto Qt = (__bf16 (*)[264])U;

    const int tid = threadIdx.x;
    const int n0 = blockIdx.x * 64;
    const int b = n0 >> 14, hw0 = n0 & 16383;
    const int lane = tid & 63, wid = tid >> 6;   // wid 0..7
    const int fr = lane & 15, kg = (lane >> 4) << 3, mrow = (lane >> 4) << 2;
    const int mbase = wid * 16;

    // stage y1 tile (NHWC bf16, coalesced): 16 bf16 per thread
    {
        int n = tid >> 3, ks = (tid & 7) * 16;
        const __bf16* src = g_y1 + (size_t)(n0 + n) * 128 + ks;
        *(bf16x8*)&Bt[n][ks]     = *(const bf16x8*)src;
        *(bf16x8*)&Bt[n][ks + 8] = *(const bf16x8*)(src + 8);
    }
    __syncthreads();

    // ---- gemm0: p = (W3.y1 + pb3)*y1 + y1 -> Pt ----
    {
        f32x4 acc[4];
#pragma unroll
        for (int nt = 0; nt < 4; ++nt)
#pragma unroll
            for (int r = 0; r < 4; ++r) acc[nt][r] = 0.f;
#pragma unroll
        for (int k0 = 0; k0 < 128; k0 += 32) {
            bf16x8 af = *(const bf16x8*)&g_w[155648 + (size_t)(mbase + fr) * 128 + k0 + kg];
            bf16x8 bfr[4];
#pragma unroll
            for (int nt = 0; nt < 4; ++nt)
                bfr[nt] = *(const bf16x8*)&Bt[nt * 16 + fr][k0 + kg];
#pragma unroll
            for (int nt = 0; nt < 4; ++nt)
                acc[nt] = __builtin_amdgcn_mfma_f32_16x16x32_bf16(af, bfr[nt], acc[nt], 0, 0, 0);
        }
        int m = mbase + mrow;
        f32x4 b3 = *(const f32x4*)&pb3[m];
#pragma unroll
        for (int nt = 0; nt < 4; ++nt) {
            int nl = nt * 16 + fr;
            bf16x4 yv = *(const bf16x4*)&Bt[nl][m];
            bf16x4 o;
#pragma unroll
            for (int r = 0; r < 4; ++r) {
                float y = (float)yv[r];
                o[r] = (__bf16)((acc[nt][r] + b3[r]) * y + y);
            }
            *(bf16x4*)&Pt[nl][m] = o;
        }
    }
    __syncthreads();

    // ---- gemm2: q = gelu(W1[256][128].p + pb1) -> Qt (k-outer, r22) ----
    {
        f32x4 acc[2][4];   // [mh][nt]
#pragma unroll
        for (int mh = 0; mh < 2; ++mh)
#pragma unroll
            for (int nt = 0; nt < 4; ++nt)
#pragma unroll
                for (int r = 0; r < 4; ++r) acc[mh][nt][r] = 0.f;
#pragma unroll
        for (int k0 = 0; k0 < 128; k0 += 32) {
            size_t wrow = (size_t)(mbase + fr) * 128 + k0 + kg;
            bf16x8 af0 = *(const bf16x8*)&g_w[65536 + wrow];            // mh=0
            bf16x8 af1 = *(const bf16x8*)&g_w[65536 + 16384 + wrow];    // mh=1 (+128 rows)
            bf16x8 bfr[4];
#pragma unroll
            for (int nt = 0; nt < 4; ++nt)
                bfr[nt] = *(const bf16x8*)&Pt[nt * 16 + fr][k0 + kg];
#pragma unroll
            for (int nt = 0; nt < 4; ++nt) {
                acc[0][nt] = __builtin_amdgcn_mfma_f32_16x16x32_bf16(af0, bfr[nt], acc[0][nt], 0, 0, 0);
                acc[1][nt] = __builtin_amdgcn_mfma_f32_16x16x32_bf16(af1, bfr[nt], acc[1][nt], 0, 0, 0);
            }
        }
        __syncthreads();   // all Pt reads done -> safe to overwrite as Qt
#pragma unroll
        for (int mh = 0; mh < 2; ++mh) {
            int m = mh * 128 + mbase + mrow;
            f32x4 b1 = *(const f32x4*)&pb1[m];
#pragma unroll
            for (int nt = 0; nt < 4; ++nt) {
                int nl = nt * 16 + fr;
                bf16x4 o;
#pragma unroll
                for (int r = 0; r < 4; ++r)
                    o[r] = (__bf16)fast_gelu(acc[mh][nt][r] + b1[r]);
                *(bf16x4*)&Qt[nl][m] = o;
            }
        }
    }
    __syncthreads();

    // ---- gemm3: out = W2[128][256].q + pb2 + y1*sig  (NCHW f32 store) ----
    {
        f32x4 acc[4];
#pragma unroll
        for (int nt = 0; nt < 4; ++nt)
#pragma unroll
            for (int r = 0; r < 4; ++r) acc[nt][r] = 0.f;
#pragma unroll
        for (int k0 = 0; k0 < 256; k0 += 32) {
            bf16x8 af = *(const bf16x8*)&g_w[98304 + (size_t)(mbase + fr) * 256 + k0 + kg];
            bf16x8 bfr[4];
#pragma unroll
            for (int nt = 0; nt < 4; ++nt)
                bfr[nt] = *(const bf16x8*)&Qt[nt * 16 + fr][k0 + kg];
#pragma unroll
            for (int nt = 0; nt < 4; ++nt)
                acc[nt] = __builtin_amdgcn_mfma_f32_16x16x32_bf16(af, bfr[nt], acc[nt], 0, 0, 0);
        }
        int m = mbase + mrow;
        f32x4 b2 = *(const f32x4*)&pb2[m];
#pragma unroll
        for (int nt = 0; nt < 4; ++nt) {
            int hw = hw0 + nt * 16 + fr;
            size_t pbase = (size_t)(n0 + nt * 16 + fr) * 128;
            bf16x4 yv = *(const bf16x4*)&g_y1[pbase + m];
            bf16x4 sv = *(const bf16x4*)&g_S[pbase + m];
#pragma unroll
            for (int r = 0; r < 4; ++r) {
                out[(size_t)(b * 128 + m + r) * kHW + hw] =
                    acc[nt][r] + b2[r] + (float)yv[r] * (float)sv[r];
            }
        }
    }
}

// ---------------------------------------------------------------------------
extern "C" void kernel_launch(void* const* d_in, const int* in_sizes, int n_in,
                              void* d_out, int out_size, void* d_ws, size_t ws_size,
                              hipStream_t stream)
{
    const float* x    = (const float*)d_in[0];
    const float* d1w  = (const float*)d_in[1];
    const float* d1b  = (const float*)d_in[2];
    const float* d4w  = (const float*)d_in[3];
    const float* d4b  = (const float*)d_in[4];
    const float* pa   = (const float*)d_in[5];
    const float* f1w1 = (const float*)d_in[6];
    const float* f1b1 = (const float*)d_in[7];
    const float* f1w2 = (const float*)d_in[8];
    const float* f1b2 = (const float*)d_in[9];
    const float* f2w1 = (const float*)d_in[10];
    const float* f2b1 = (const float*)d_in[11];
    const float* f2w2 = (const float*)d_in[12];
    const float* f2b2 = (const float*)d_in[13];
    const float* pw1  = (const float*)d_in[14];
    const float* pb1  = (const float*)d_in[15];
    const float* pw2  = (const float*)d_in[16];
    const float* pb2  = (const float*)d_in[17];
    const float* pw3  = (const float*)d_in[18];
    const float* pb3  = (const float*)d_in[19];
    float* out = (float*)d_out;

    k_prepw<<<672, 256, 0, stream>>>(f1w1, f1w2, f2w1, f2w2, pw1, pw2, d1w, d4w, pw3);
    k_fused<<<1024, 512, 0, stream>>>(x, d1b, d4b, pa, f1b1, f1b2, f2b1, f2b2);
    k_scan_par<<<1024, 256, 0, stream>>>();
    k_mega<<<1024, 512, 0, stream>>>(pb3, pb1, pb2, out);

    (void)in_sizes; (void)n_in; (void)d_ws; (void)ws_size; (void)out_size;
}